// Round 14
// baseline (448.909 us; speedup 1.0000x reference)
//
#include <hip/hip_runtime.h>

#define NN 50000
#define NE 800000

__device__ __forceinline__ float sigm(float v) { return 1.0f / (1.0f + __expf(-v)); }

using vfloat4 = float __attribute__((ext_vector_type(4)));

// ===========================================================================
// Hierarchical exclusive scan over n=100000 bins, 2048 elems/block.
// ===========================================================================
__global__ void scan_k1(const int* __restrict__ cnt, int n, int* __restrict__ bsum)
{
    __shared__ int s[256];
    int t = threadIdx.x;
    int base = blockIdx.x * 2048 + t * 8;
    int sum = 0;
#pragma unroll
    for (int q = 0; q < 8; ++q) { int idx = base + q; if (idx < n) sum += cnt[idx]; }
    s[t] = sum;
    __syncthreads();
#pragma unroll
    for (int d = 128; d; d >>= 1) { if (t < d) s[t] += s[t + d]; __syncthreads(); }
    if (t == 0) bsum[blockIdx.x] = s[0];
}

__global__ void scan_k2(int* __restrict__ bsum, int nblocks)
{
    __shared__ int s[512];
    int t = threadIdx.x;
    int v = (t < nblocks) ? bsum[t] : 0;
    s[t] = v;
    __syncthreads();
#pragma unroll
    for (int d = 1; d < 512; d <<= 1) {
        int a = (t >= d) ? s[t - d] : 0;
        __syncthreads();
        s[t] += a;
        __syncthreads();
    }
    if (t < nblocks) bsum[t] = s[t] - v;   // exclusive
}

__global__ void scan_k3(const int* __restrict__ cnt, int n,
                        const int* __restrict__ bsum, int* __restrict__ offset)
{
    __shared__ int s[256];
    int t = threadIdx.x;
    int base = blockIdx.x * 2048 + t * 8;
    int v[8]; int sum = 0;
#pragma unroll
    for (int q = 0; q < 8; ++q) {
        int idx = base + q;
        v[q] = (idx < n) ? cnt[idx] : 0;
        sum += v[q];
    }
    s[t] = sum;
    __syncthreads();
#pragma unroll
    for (int d = 1; d < 256; d <<= 1) {
        int a = (t >= d) ? s[t - d] : 0;
        __syncthreads();
        s[t] += a;
        __syncthreads();
    }
    int run = bsum[blockIdx.x] + ((t > 0) ? s[t - 1] : 0);
#pragma unroll
    for (int q = 0; q < 8; ++q) {
        int idx = base + q;
        if (idx <= n) offset[idx] = run;
        run += v[q];
    }
}

// ===========================================================================
// build_ranks: standalone; ~22G atomics/s coherence-pipe floor (R7-R12).
// ===========================================================================
__global__ void build_ranks(const int* __restrict__ ei,
                            int* __restrict__ cnt,
                            unsigned short* __restrict__ rank_s,
                            unsigned short* __restrict__ rank_d)
{
    int e = blockIdx.x * 256 + threadIdx.x;   // NE == 3125*256 exactly
    int s = ei[e], d = ei[NE + e];
    rank_d[e] = (unsigned short)atomicAdd(cnt + d, 1);
    rank_s[e] = (unsigned short)atomicAdd(cnt + NN + s, 1);
}

// ===========================================================================
// build_perm: scattered partial-line stores -> NON-TEMPORAL to bypass
// L2 write-allocate/RFO (R5 signature: FETCH ~= written-buffer size).
// ===========================================================================
__global__ void build_perm(const int* __restrict__ ei,
                           const float* __restrict__ ea,
                           const int* __restrict__ off_all,
                           const unsigned short* __restrict__ rank_s,
                           const unsigned short* __restrict__ rank_d,
                           unsigned long long* __restrict__ pack,
                           float* __restrict__ ea_s)
{
    int e = blockIdx.x * 256 + threadIdx.x;
    int s = ei[e], d = ei[NE + e];
    int spos = off_all[NN + s] - NE + (int)rank_s[e];
    int dp   = off_all[d] + (int)rank_d[e];
    unsigned long long pk = (unsigned)s | ((unsigned long long)(unsigned)dp << 32);
    __builtin_nontemporal_store(pk, pack + spos);
    vfloat4 av = *(const vfloat4*)(ea + (size_t)e * 4);
    __builtin_nontemporal_store(av, (vfloat4*)(ea_s + (size_t)spos * 4));
}

// ===========================================================================
// edge_fusedG<DIN>: block = out-edges of src nodes [16b,16b+16) (src-CSR).
// Phase 1: G for these 16 nodes INTO LDS, reading eW2 DIRECTLY from global
// (L1/L2 broadcast-served; removes the 10-20 KB w2L staging union ->
// LDS 41.5->38.7 KB -> 4 blocks/CU instead of 3).
// Phase 2: chunked edge loop; LDS remap -> full-64B-row stores to msgbuf.
// xbL padded to stride 5 (kills 8-way bank alias seen in R13).
// ===========================================================================
template<int DIN>
__global__ __launch_bounds__(256) void edge_fusedG(
        const float* __restrict__ xin,    // [NN][DIN]
        const uint2* __restrict__ pack,   // [NE] {src,dstpos} src-sorted
        const float* __restrict__ ea_s,   // [NE][4] src-sorted
        const float* __restrict__ eW1,    // [4][16]
        const float* __restrict__ eb1,    // [16]
        const float* __restrict__ eW2,    // [16][DIN*16]
        const float* __restrict__ eb2,    // [DIN*16]
        const int*   __restrict__ off_all,// src CSR at off_all[NN+s]
        float* __restrict__ msgbuf)       // [NE][16] dst-sorted rows
{
    constexpr int MROW = 260;
    __shared__ __align__(16) float smemM[16 * MROW];
    __shared__ __align__(16) int   sdp[256];
    __shared__ __align__(16) float4 G4[16 * 69];       // [sl*69 + ob*17 + k]
    __shared__ __align__(16) float4 xbL[16 * 5];       // [sl*5 + ob] (pad 5)
    __shared__ __align__(16) float  xL[16 * DIN];
    __shared__ __align__(16) float  b2L[DIN * 16];
    __shared__ __align__(16) float4 w1t[16];
    __shared__ __align__(16) float  b1s[16];

    int tid = threadIdx.x;
    int nb  = blockIdx.x * 16;
    if (tid < 16) {
        w1t[tid] = make_float4(eW1[tid], eW1[16 + tid], eW1[32 + tid], eW1[48 + tid]);
        b1s[tid] = eb1[tid];
    }
    for (int t = tid; t < DIN * 16; t += 256) b2L[t] = eb2[t];
    for (int t = tid; t < 16 * DIN; t += 256) xL[t] = xin[(size_t)nb * DIN + t];
    __syncthreads();

    {   // phase 1: thread (nl, k); eW2 quads read directly from global
        int nl = tid >> 4, k = tid & 15;
        const float* xrow = xL + nl * DIN;
        const float4* w2g = (const float4*)eW2;   // quad idx (k*DIN+i)*4 + ob
#pragma unroll
        for (int ob = 0; ob < 4; ++ob) {
            float4 a4 = make_float4(0.f, 0.f, 0.f, 0.f);
#pragma unroll
            for (int i = 0; i < DIN; ++i) {
                float4 w = w2g[(k * DIN + i) * 4 + ob];
                a4.x += xrow[i] * w.x; a4.y += xrow[i] * w.y;
                a4.z += xrow[i] * w.z; a4.w += xrow[i] * w.w;
            }
            G4[nl * 69 + ob * 17 + k] = a4;
        }
        if (k < 4) {
            int ob = k;
            const float4* b2v = (const float4*)b2L;
            float4 a4 = make_float4(0.f, 0.f, 0.f, 0.f);
#pragma unroll
            for (int i = 0; i < DIN; ++i) {
                float4 b = b2v[i * 4 + ob];
                a4.x += xrow[i] * b.x; a4.y += xrow[i] * b.y;
                a4.z += xrow[i] * b.z; a4.w += xrow[i] * b.w;
            }
            xbL[nl * 5 + ob] = a4;
        }
    }
    __syncthreads();

    // phase 2: chunked edge loop over the block's src-CSR range
    int eBeg = off_all[NN + nb] - NE;
    int eEnd = off_all[NN + nb + 16] - NE;
    for (int cb = eBeg; cb < eEnd; cb += 256) {
        int pos = cb + tid;
        bool valid = pos < eEnd;
        uint2 pe = valid ? pack[pos] : make_uint2((unsigned)nb, 0u);
        float4 a = valid ? ((const float4*)ea_s)[pos] : make_float4(0.f, 0.f, 0.f, 0.f);

        float h[16];
#pragma unroll
        for (int j = 0; j < 16; ++j) {
            float4 w = w1t[j];
            float p = b1s[j] + a.x * w.x + a.y * w.y + a.z * w.z + a.w * w.w;
            h[j] = p * sigm(p);
        }
        int sl = (int)pe.x - nb;
        float4 acc[4];
#pragma unroll
        for (int ob = 0; ob < 4; ++ob) acc[ob] = xbL[sl * 5 + ob];
#pragma unroll
        for (int k = 0; k < 16; ++k) {
            float hk = h[k];
#pragma unroll
            for (int ob = 0; ob < 4; ++ob) {
                float4 g = G4[sl * 69 + ob * 17 + k];
                acc[ob].x += hk * g.x; acc[ob].y += hk * g.y;
                acc[ob].z += hk * g.z; acc[ob].w += hk * g.w;
            }
        }
        sdp[tid] = valid ? (int)pe.y : -1;
#pragma unroll
        for (int ob = 0; ob < 4; ++ob) {
            smemM[(ob * 4 + 0) * MROW + tid] = acc[ob].x;
            smemM[(ob * 4 + 1) * MROW + tid] = acc[ob].y;
            smemM[(ob * 4 + 2) * MROW + tid] = acc[ob].z;
            smemM[(ob * 4 + 3) * MROW + tid] = acc[ob].w;
        }
        __syncthreads();
#pragma unroll
        for (int r = 0; r < 16; ++r) {
            int le = r * 16 + (tid >> 4);
            int ch = tid & 15;
            int dp = sdp[le];                      // 16-lane broadcast
            float v = smemM[ch * MROW + le];       // 2 lanes/bank: free
            if (dp >= 0) msgbuf[(size_t)dp * 16 + ch] = v;  // full 64B rows
        }
        __syncthreads();
    }
}

// ===========================================================================
// gather_L0: tiny-LDS, high-occupancy (R13 lesson: keep latency-bound
// gather OUT of the big-LDS edge kernel).
// ===========================================================================
__global__ __launch_bounds__(256) void gather_L0(
        const float* __restrict__ xin,    // [NN][8]
        const float* __restrict__ root,   // [8][16]
        const float* __restrict__ bias,   // [16]
        const int*   __restrict__ off_all,
        const float* __restrict__ msgbuf,
        float* __restrict__ x1)           // [NN][16]
{
    __shared__ __align__(16) float rootL[8 * 16];
    __shared__ __align__(16) float biasL[16];
    int tid = threadIdx.x;
    if (tid < 128) rootL[tid] = root[tid];
    if (tid < 16) biasL[tid] = bias[tid];
    __syncthreads();

    int ch = tid & 15;
    int n  = blockIdx.x * 16 + (tid >> 4);
    int s0 = off_all[n], e0 = off_all[n + 1];

    float acc = 0.f;
    for (int j = s0; j < e0; ++j)
        acc += msgbuf[(size_t)j * 16 + ch];
    float v = acc / fmaxf((float)(e0 - s0), 1.0f) + biasL[ch];
#pragma unroll
    for (int i = 0; i < 8; ++i)
        v += xin[(size_t)n * 8 + i] * rootL[i * 16 + ch];
    x1[(size_t)n * 16 + ch] = fmaxf(v, 0.f);
}

// ===========================================================================
// gather_final: contiguous dst-row sums + node update + output MLP.
// ===========================================================================
__global__ __launch_bounds__(256) void gather_final(
        const float* __restrict__ x1,     // [NN][16]
        const float* __restrict__ root,   // [16][16]
        const float* __restrict__ bias,   // [16]
        const int*   __restrict__ off_all,
        const float* __restrict__ msgbuf,
        const float* __restrict__ mW1,    // [16][16]
        const float* __restrict__ mb1,    // [16]
        const float* __restrict__ mW2,    // [16]
        const float* __restrict__ mb2,    // [1]
        float* __restrict__ out)          // [NN]
{
    __shared__ __align__(16) float rootL[256];
    __shared__ __align__(16) float biasL[16];
    __shared__ __align__(16) float w1m[256];
    __shared__ __align__(16) float b1m[16];
    __shared__ __align__(16) float w2m[16];
    __shared__ float b2m;
    int tid = threadIdx.x;
    rootL[tid] = root[tid];
    w1m[tid] = mW1[tid];
    if (tid < 16) { biasL[tid] = bias[tid]; b1m[tid] = mb1[tid]; w2m[tid] = mW2[tid]; }
    if (tid == 0) b2m = mb2[0];
    __syncthreads();

    int ch = tid & 15;
    int n  = blockIdx.x * 16 + (tid >> 4);
    int s0 = off_all[n], e0 = off_all[n + 1];

    float acc = 0.f;
    for (int j = s0; j < e0; ++j)
        acc += msgbuf[(size_t)j * 16 + ch];
    float v = acc / fmaxf((float)(e0 - s0), 1.0f) + biasL[ch];
#pragma unroll
    for (int i = 0; i < 16; ++i)
        v += x1[(size_t)n * 16 + i] * rootL[i * 16 + ch];
    v = fmaxf(v, 0.f);

    float z = b1m[ch];
#pragma unroll
    for (int o = 0; o < 16; ++o) {
        float vo = __shfl(v, o, 16);
        z += vo * w1m[o * 16 + ch];
    }
    float ss = z * sigm(z) * w2m[ch];
#pragma unroll
    for (int off = 8; off; off >>= 1) ss += __shfl_xor(ss, off, 16);
    if (ch == 0) out[n] = sigm(ss + b2m);
}

// ===========================================================================
// Host launch
// ===========================================================================
extern "C" void kernel_launch(void* const* d_in, const int* in_sizes, int n_in,
                              void* d_out, int out_size, void* d_ws, size_t ws_size,
                              hipStream_t stream) {
    const float* x     = (const float*)d_in[0];
    const int*   ei    = (const int*)  d_in[1];
    const float* ea    = (const float*)d_in[2];
    const float* eW1_0 = (const float*)d_in[3];
    const float* eb1_0 = (const float*)d_in[4];
    const float* eW2_0 = (const float*)d_in[5];
    const float* eb2_0 = (const float*)d_in[6];
    const float* root0 = (const float*)d_in[7];
    const float* bias0 = (const float*)d_in[8];
    const float* eW1_1 = (const float*)d_in[9];
    const float* eb1_1 = (const float*)d_in[10];
    const float* eW2_1 = (const float*)d_in[11];
    const float* eb2_1 = (const float*)d_in[12];
    const float* root1 = (const float*)d_in[13];
    const float* bias1 = (const float*)d_in[14];
    const float* mW1   = (const float*)d_in[15];
    const float* mb1   = (const float*)d_in[16];
    const float* mW2   = (const float*)d_in[17];
    const float* mb2   = (const float*)d_in[18];
    float* out = (float*)d_out;

    const int EG = NE / 256;   // 3125
    const int GG = NN / 16;    // 3125
    const int SN = 2 * NN;              // 100000 bins
    const int SB = (SN + 2047) / 2048;  // 49

    // ---- ws layout (4B words), total ~19.3M words = 77 MB ----
    int* W = (int*)d_ws;
    int*   off_all = W;                       // 100001 -> pad 100004
    int*   bsum    = W + 100004;              // 512
    unsigned short* rank_s = (unsigned short*)(W + 100516);  // NE u16
    unsigned short* rank_d = (unsigned short*)(W + 500516);  // NE u16
    unsigned long long* pack = (unsigned long long*)(W + 900516); // NE u64
    float* ea_s    = (float*)(W + 2500516);   // [NE][4]
    float* x1      = (float*)(W + 5700516);   // [NN][16]
    float* msgbuf  = (float*)(W + 6500516);   // [NE][16]
    int*   cnt     = W + 6500516;             // SN ints, overlaid on msgbuf

    hipMemsetAsync(cnt, 0, SN * sizeof(int), stream);
    build_ranks<<<EG, 256, 0, stream>>>(ei, cnt, rank_s, rank_d);
    scan_k1<<<SB, 256, 0, stream>>>(cnt, SN, bsum);
    scan_k2<<<1, 512, 0, stream>>>(bsum, SB);
    scan_k3<<<SB, 256, 0, stream>>>(cnt, SN, bsum, off_all);
    build_perm<<<EG, 256, 0, stream>>>(ei, ea, off_all, rank_s, rank_d, pack, ea_s);

    // ---- layer 0 ----
    edge_fusedG<8><<<GG, 256, 0, stream>>>(x, (const uint2*)pack, ea_s, eW1_0, eb1_0,
                                           eW2_0, eb2_0, off_all, msgbuf);
    gather_L0<<<GG, 256, 0, stream>>>(x, root0, bias0, off_all, msgbuf, x1);

    // ---- layer 1 ----
    edge_fusedG<16><<<GG, 256, 0, stream>>>(x1, (const uint2*)pack, ea_s, eW1_1, eb1_1,
                                            eW2_1, eb2_1, off_all, msgbuf);
    gather_final<<<GG, 256, 0, stream>>>(x1, root1, bias1, off_all, msgbuf,
                                         mW1, mb1, mW2, mb2, out);
}

// Round 15
// 329.767 us; speedup vs baseline: 1.3613x; 1.3613x over previous
//
#include <hip/hip_runtime.h>

#define NN 50000
#define NE 800000

__device__ __forceinline__ float sigm(float v) { return 1.0f / (1.0f + __expf(-v)); }

// ===========================================================================
// Hierarchical exclusive scan over n=100000 bins, 2048 elems/block.
// ===========================================================================
__global__ void scan_k1(const int* __restrict__ cnt, int n, int* __restrict__ bsum)
{
    __shared__ int s[256];
    int t = threadIdx.x;
    int base = blockIdx.x * 2048 + t * 8;
    int sum = 0;
#pragma unroll
    for (int q = 0; q < 8; ++q) { int idx = base + q; if (idx < n) sum += cnt[idx]; }
    s[t] = sum;
    __syncthreads();
#pragma unroll
    for (int d = 128; d; d >>= 1) { if (t < d) s[t] += s[t + d]; __syncthreads(); }
    if (t == 0) bsum[blockIdx.x] = s[0];
}

__global__ void scan_k2(int* __restrict__ bsum, int nblocks)
{
    __shared__ int s[512];
    int t = threadIdx.x;
    int v = (t < nblocks) ? bsum[t] : 0;
    s[t] = v;
    __syncthreads();
#pragma unroll
    for (int d = 1; d < 512; d <<= 1) {
        int a = (t >= d) ? s[t - d] : 0;
        __syncthreads();
        s[t] += a;
        __syncthreads();
    }
    if (t < nblocks) bsum[t] = s[t] - v;   // exclusive
}

__global__ void scan_k3(const int* __restrict__ cnt, int n,
                        const int* __restrict__ bsum, int* __restrict__ offset)
{
    __shared__ int s[256];
    int t = threadIdx.x;
    int base = blockIdx.x * 2048 + t * 8;
    int v[8]; int sum = 0;
#pragma unroll
    for (int q = 0; q < 8; ++q) {
        int idx = base + q;
        v[q] = (idx < n) ? cnt[idx] : 0;
        sum += v[q];
    }
    s[t] = sum;
    __syncthreads();
#pragma unroll
    for (int d = 1; d < 256; d <<= 1) {
        int a = (t >= d) ? s[t - d] : 0;
        __syncthreads();
        s[t] += a;
        __syncthreads();
    }
    int run = bsum[blockIdx.x] + ((t > 0) ? s[t - 1] : 0);
#pragma unroll
    for (int q = 0; q < 8; ++q) {
        int idx = base + q;
        if (idx <= n) offset[idx] = run;
        run += v[q];
    }
}

// ===========================================================================
// build_ranks: standalone; ~22G atomics/s coherence-pipe floor (R7-R12).
// ===========================================================================
__global__ void build_ranks(const int* __restrict__ ei,
                            int* __restrict__ cnt,
                            unsigned short* __restrict__ rank_s,
                            unsigned short* __restrict__ rank_d)
{
    int e = blockIdx.x * 256 + threadIdx.x;   // NE == 3125*256 exactly
    int s = ei[e], d = ei[NE + e];
    rank_d[e] = (unsigned short)atomicAdd(cnt + d, 1);
    rank_s[e] = (unsigned short)atomicAdd(cnt + NN + s, 1);
}

// ===========================================================================
// build_perm: normal stores (R14 lesson: nt stores evict L2 warmth for the
// downstream edge-kernel reads; revert to R12-proven form).
// ===========================================================================
__global__ void build_perm(const int* __restrict__ ei,
                           const float* __restrict__ ea,
                           const int* __restrict__ off_all,
                           const unsigned short* __restrict__ rank_s,
                           const unsigned short* __restrict__ rank_d,
                           uint2* __restrict__ pack,
                           float* __restrict__ ea_s)
{
    int e = blockIdx.x * 256 + threadIdx.x;
    int s = ei[e], d = ei[NE + e];
    int spos = off_all[NN + s] - NE + (int)rank_s[e];
    int dp   = off_all[d] + (int)rank_d[e];
    pack[spos] = make_uint2((unsigned)s, (unsigned)dp);
    ((float4*)ea_s)[spos] = ((const float4*)ea)[e];
}

// ===========================================================================
// edge_fusedG<DIN>: block = out-edges of src nodes [16b,16b+16) (src-CSR).
// Phase 1: G for these 16 nodes INTO LDS from LDS-staged w2 (R14 lesson:
// direct-global phase 1 = 51M scattered vmem loads, 2x slower).
// Phase 2: chunked edge loop; LDS remap -> full-64B-row stores to msgbuf.
// xbL padded to stride 5 (kills the 8-way bank alias seen in R13).
// ===========================================================================
template<int DIN>
__global__ __launch_bounds__(256) void edge_fusedG(
        const float* __restrict__ xin,    // [NN][DIN]
        const uint2* __restrict__ pack,   // [NE] {src,dstpos} src-sorted
        const float* __restrict__ ea_s,   // [NE][4] src-sorted
        const float* __restrict__ eW1,    // [4][16]
        const float* __restrict__ eb1,    // [16]
        const float* __restrict__ eW2,    // [16][DIN*16]
        const float* __restrict__ eb2,    // [DIN*16]
        const int*   __restrict__ off_all,// src CSR at off_all[NN+s]
        float* __restrict__ msgbuf)       // [NE][16] dst-sorted rows
{
    constexpr int MROW = 260;
    constexpr int W2B  = DIN * 16 * 20 * 4;           // w2L bytes (phase 1)
    constexpr int SMB  = 16 * MROW * 4 + 256 * 4;     // smemM + sdp (phase 2)
    constexpr int UNIB = (W2B > SMB) ? W2B : SMB;
    __shared__ __align__(16) char uni[UNIB];
    float* w2L   = (float*)uni;                        // [(i*16+k)*20 + o]
    float* smemM = (float*)uni;                        // [16][MROW]
    int*   sdp   = (int*)(uni + 16 * MROW * 4);        // [256]
    __shared__ __align__(16) float4 G4[16 * 69];       // [sl*69 + ob*17 + k]
    __shared__ __align__(16) float4 xbL[16 * 5];       // [sl*5 + ob] (pad 5)
    __shared__ __align__(16) float  xL[16 * DIN];
    __shared__ __align__(16) float  b2L[DIN * 16];
    __shared__ __align__(16) float4 w1t[16];
    __shared__ __align__(16) float  b1s[16];

    int tid = threadIdx.x;
    int nb  = blockIdx.x * 16;                // first src node of block
    if (tid < 16) {
        w1t[tid] = make_float4(eW1[tid], eW1[16 + tid], eW1[32 + tid], eW1[48 + tid]);
        b1s[tid] = eb1[tid];
    }
    for (int t = tid; t < 16 * DIN * 16; t += 256) {
        int k = t / (DIN * 16);
        int rem = t - k * DIN * 16;
        int i = rem >> 4, o = rem & 15;
        w2L[(i * 16 + k) * 20 + o] = eW2[t];
    }
    for (int t = tid; t < DIN * 16; t += 256) b2L[t] = eb2[t];
    for (int t = tid; t < 16 * DIN; t += 256) xL[t] = xin[(size_t)nb * DIN + t];
    __syncthreads();

    // ---- phase 1: G + xb for 16 local nodes; thread (nl, k) ----
    {
        int nl = tid >> 4, k = tid & 15;
        const float* xrow = xL + nl * DIN;
#pragma unroll
        for (int ob = 0; ob < 4; ++ob) {
            float4 a4 = make_float4(0.f, 0.f, 0.f, 0.f);
#pragma unroll
            for (int i = 0; i < DIN; ++i) {
                const float4 w = *((const float4*)(w2L + (i * 16 + k) * 20) + ob);
                a4.x += xrow[i] * w.x; a4.y += xrow[i] * w.y;
                a4.z += xrow[i] * w.z; a4.w += xrow[i] * w.w;
            }
            G4[nl * 69 + ob * 17 + k] = a4;
        }
        if (k < 4) {
            int ob = k;
            const float4* b2v = (const float4*)b2L;
            float4 a4 = make_float4(0.f, 0.f, 0.f, 0.f);
#pragma unroll
            for (int i = 0; i < DIN; ++i) {
                float4 b = b2v[i * 4 + ob];
                a4.x += xrow[i] * b.x; a4.y += xrow[i] * b.y;
                a4.z += xrow[i] * b.z; a4.w += xrow[i] * b.w;
            }
            xbL[nl * 5 + ob] = a4;
        }
    }
    __syncthreads();   // w2L dead; uni becomes smemM/sdp

    // ---- phase 2: chunked edge loop over this block's src-CSR range ----
    int eBeg = off_all[NN + nb] - NE;
    int eEnd = off_all[NN + nb + 16] - NE;
    for (int cb = eBeg; cb < eEnd; cb += 256) {
        int pos = cb + tid;
        bool valid = pos < eEnd;
        uint2 pe = valid ? pack[pos] : make_uint2((unsigned)nb, 0u);
        float4 a = valid ? ((const float4*)ea_s)[pos] : make_float4(0.f, 0.f, 0.f, 0.f);

        float h[16];
#pragma unroll
        for (int j = 0; j < 16; ++j) {
            float4 w = w1t[j];
            float p = b1s[j] + a.x * w.x + a.y * w.y + a.z * w.z + a.w * w.w;
            h[j] = p * sigm(p);
        }
        int sl = (int)pe.x - nb;
        float4 acc[4];
#pragma unroll
        for (int ob = 0; ob < 4; ++ob) acc[ob] = xbL[sl * 5 + ob];
#pragma unroll
        for (int k = 0; k < 16; ++k) {
            float hk = h[k];
#pragma unroll
            for (int ob = 0; ob < 4; ++ob) {
                float4 g = G4[sl * 69 + ob * 17 + k];
                acc[ob].x += hk * g.x; acc[ob].y += hk * g.y;
                acc[ob].z += hk * g.z; acc[ob].w += hk * g.w;
            }
        }
        sdp[tid] = valid ? (int)pe.y : -1;
#pragma unroll
        for (int ob = 0; ob < 4; ++ob) {
            smemM[(ob * 4 + 0) * MROW + tid] = acc[ob].x;
            smemM[(ob * 4 + 1) * MROW + tid] = acc[ob].y;
            smemM[(ob * 4 + 2) * MROW + tid] = acc[ob].z;
            smemM[(ob * 4 + 3) * MROW + tid] = acc[ob].w;
        }
        __syncthreads();
#pragma unroll
        for (int r = 0; r < 16; ++r) {
            int le = r * 16 + (tid >> 4);
            int ch = tid & 15;
            int dp = sdp[le];                      // 16-lane broadcast
            float v = smemM[ch * MROW + le];       // 2 lanes/bank: free
            if (dp >= 0) msgbuf[(size_t)dp * 16 + ch] = v;  // full 64B rows
        }
        __syncthreads();
    }
}

// ===========================================================================
// gather_L0: tiny-LDS, high-occupancy (R13 lesson: keep latency-bound
// gather OUT of the big-LDS edge kernel).
// ===========================================================================
__global__ __launch_bounds__(256) void gather_L0(
        const float* __restrict__ xin,    // [NN][8]
        const float* __restrict__ root,   // [8][16]
        const float* __restrict__ bias,   // [16]
        const int*   __restrict__ off_all,
        const float* __restrict__ msgbuf,
        float* __restrict__ x1)           // [NN][16]
{
    __shared__ __align__(16) float rootL[8 * 16];
    __shared__ __align__(16) float biasL[16];
    int tid = threadIdx.x;
    if (tid < 128) rootL[tid] = root[tid];
    if (tid < 16) biasL[tid] = bias[tid];
    __syncthreads();

    int ch = tid & 15;
    int n  = blockIdx.x * 16 + (tid >> 4);
    int s0 = off_all[n], e0 = off_all[n + 1];

    float acc = 0.f;
    for (int j = s0; j < e0; ++j)
        acc += msgbuf[(size_t)j * 16 + ch];
    float v = acc / fmaxf((float)(e0 - s0), 1.0f) + biasL[ch];
#pragma unroll
    for (int i = 0; i < 8; ++i)
        v += xin[(size_t)n * 8 + i] * rootL[i * 16 + ch];
    x1[(size_t)n * 16 + ch] = fmaxf(v, 0.f);
}

// ===========================================================================
// gather_final: contiguous dst-row sums + node update + output MLP.
// ===========================================================================
__global__ __launch_bounds__(256) void gather_final(
        const float* __restrict__ x1,     // [NN][16]
        const float* __restrict__ root,   // [16][16]
        const float* __restrict__ bias,   // [16]
        const int*   __restrict__ off_all,
        const float* __restrict__ msgbuf,
        const float* __restrict__ mW1,    // [16][16]
        const float* __restrict__ mb1,    // [16]
        const float* __restrict__ mW2,    // [16]
        const float* __restrict__ mb2,    // [1]
        float* __restrict__ out)          // [NN]
{
    __shared__ __align__(16) float rootL[256];
    __shared__ __align__(16) float biasL[16];
    __shared__ __align__(16) float w1m[256];
    __shared__ __align__(16) float b1m[16];
    __shared__ __align__(16) float w2m[16];
    __shared__ float b2m;
    int tid = threadIdx.x;
    rootL[tid] = root[tid];
    w1m[tid] = mW1[tid];
    if (tid < 16) { biasL[tid] = bias[tid]; b1m[tid] = mb1[tid]; w2m[tid] = mW2[tid]; }
    if (tid == 0) b2m = mb2[0];
    __syncthreads();

    int ch = tid & 15;
    int n  = blockIdx.x * 16 + (tid >> 4);
    int s0 = off_all[n], e0 = off_all[n + 1];

    float acc = 0.f;
    for (int j = s0; j < e0; ++j)
        acc += msgbuf[(size_t)j * 16 + ch];
    float v = acc / fmaxf((float)(e0 - s0), 1.0f) + biasL[ch];
#pragma unroll
    for (int i = 0; i < 16; ++i)
        v += x1[(size_t)n * 16 + i] * rootL[i * 16 + ch];
    v = fmaxf(v, 0.f);

    float z = b1m[ch];
#pragma unroll
    for (int o = 0; o < 16; ++o) {
        float vo = __shfl(v, o, 16);
        z += vo * w1m[o * 16 + ch];
    }
    float ss = z * sigm(z) * w2m[ch];
#pragma unroll
    for (int off = 8; off; off >>= 1) ss += __shfl_xor(ss, off, 16);
    if (ch == 0) out[n] = sigm(ss + b2m);
}

// ===========================================================================
// Host launch
// ===========================================================================
extern "C" void kernel_launch(void* const* d_in, const int* in_sizes, int n_in,
                              void* d_out, int out_size, void* d_ws, size_t ws_size,
                              hipStream_t stream) {
    const float* x     = (const float*)d_in[0];
    const int*   ei    = (const int*)  d_in[1];
    const float* ea    = (const float*)d_in[2];
    const float* eW1_0 = (const float*)d_in[3];
    const float* eb1_0 = (const float*)d_in[4];
    const float* eW2_0 = (const float*)d_in[5];
    const float* eb2_0 = (const float*)d_in[6];
    const float* root0 = (const float*)d_in[7];
    const float* bias0 = (const float*)d_in[8];
    const float* eW1_1 = (const float*)d_in[9];
    const float* eb1_1 = (const float*)d_in[10];
    const float* eW2_1 = (const float*)d_in[11];
    const float* eb2_1 = (const float*)d_in[12];
    const float* root1 = (const float*)d_in[13];
    const float* bias1 = (const float*)d_in[14];
    const float* mW1   = (const float*)d_in[15];
    const float* mb1   = (const float*)d_in[16];
    const float* mW2   = (const float*)d_in[17];
    const float* mb2   = (const float*)d_in[18];
    float* out = (float*)d_out;

    const int EG = NE / 256;   // 3125
    const int GG = NN / 16;    // 3125
    const int SN = 2 * NN;              // 100000 bins
    const int SB = (SN + 2047) / 2048;  // 49

    // ---- ws layout (4B words), total ~19.3M words = 77 MB ----
    int* W = (int*)d_ws;
    int*   off_all = W;                       // 100001 -> pad 100004
    int*   bsum    = W + 100004;              // 512
    unsigned short* rank_s = (unsigned short*)(W + 100516);  // NE u16
    unsigned short* rank_d = (unsigned short*)(W + 500516);  // NE u16
    uint2* pack    = (uint2*)(W + 900516);    // NE {src,dstpos} (8B-aligned)
    float* ea_s    = (float*)(W + 2500516);   // [NE][4]
    float* x1      = (float*)(W + 5700516);   // [NN][16]
    float* msgbuf  = (float*)(W + 6500516);   // [NE][16]
    int*   cnt     = W + 6500516;             // SN ints, overlaid on msgbuf

    hipMemsetAsync(cnt, 0, SN * sizeof(int), stream);
    build_ranks<<<EG, 256, 0, stream>>>(ei, cnt, rank_s, rank_d);
    scan_k1<<<SB, 256, 0, stream>>>(cnt, SN, bsum);
    scan_k2<<<1, 512, 0, stream>>>(bsum, SB);
    scan_k3<<<SB, 256, 0, stream>>>(cnt, SN, bsum, off_all);
    build_perm<<<EG, 256, 0, stream>>>(ei, ea, off_all, rank_s, rank_d, pack, ea_s);

    // ---- layer 0 ----
    edge_fusedG<8><<<GG, 256, 0, stream>>>(x, pack, ea_s, eW1_0, eb1_0,
                                           eW2_0, eb2_0, off_all, msgbuf);
    gather_L0<<<GG, 256, 0, stream>>>(x, root0, bias0, off_all, msgbuf, x1);

    // ---- layer 1 ----
    edge_fusedG<16><<<GG, 256, 0, stream>>>(x1, pack, ea_s, eW1_1, eb1_1,
                                            eW2_1, eb2_1, off_all, msgbuf);
    gather_final<<<GG, 256, 0, stream>>>(x1, root1, bias1, off_all, msgbuf,
                                         mW1, mb1, mW2, mb2, out);
}

// Round 16
// 323.121 us; speedup vs baseline: 1.3893x; 1.0206x over previous
//
#include <hip/hip_runtime.h>

#define NN 50000
#define NE 800000

__device__ __forceinline__ float sigm(float v) { return 1.0f / (1.0f + __expf(-v)); }

// ===========================================================================
// Hierarchical exclusive scan over n=100000 bins, 2048 elems/block.
// ===========================================================================
__global__ void scan_k1(const int* __restrict__ cnt, int n, int* __restrict__ bsum)
{
    __shared__ int s[256];
    int t = threadIdx.x;
    int base = blockIdx.x * 2048 + t * 8;
    int sum = 0;
#pragma unroll
    for (int q = 0; q < 8; ++q) { int idx = base + q; if (idx < n) sum += cnt[idx]; }
    s[t] = sum;
    __syncthreads();
#pragma unroll
    for (int d = 128; d; d >>= 1) { if (t < d) s[t] += s[t + d]; __syncthreads(); }
    if (t == 0) bsum[blockIdx.x] = s[0];
}

__global__ void scan_k2(int* __restrict__ bsum, int nblocks)
{
    __shared__ int s[512];
    int t = threadIdx.x;
    int v = (t < nblocks) ? bsum[t] : 0;
    s[t] = v;
    __syncthreads();
#pragma unroll
    for (int d = 1; d < 512; d <<= 1) {
        int a = (t >= d) ? s[t - d] : 0;
        __syncthreads();
        s[t] += a;
        __syncthreads();
    }
    if (t < nblocks) bsum[t] = s[t] - v;   // exclusive
}

__global__ void scan_k3(const int* __restrict__ cnt, int n,
                        const int* __restrict__ bsum, int* __restrict__ offset)
{
    __shared__ int s[256];
    int t = threadIdx.x;
    int base = blockIdx.x * 2048 + t * 8;
    int v[8]; int sum = 0;
#pragma unroll
    for (int q = 0; q < 8; ++q) {
        int idx = base + q;
        v[q] = (idx < n) ? cnt[idx] : 0;
        sum += v[q];
    }
    s[t] = sum;
    __syncthreads();
#pragma unroll
    for (int d = 1; d < 256; d <<= 1) {
        int a = (t >= d) ? s[t - d] : 0;
        __syncthreads();
        s[t] += a;
        __syncthreads();
    }
    int run = bsum[blockIdx.x] + ((t > 0) ? s[t - 1] : 0);
#pragma unroll
    for (int q = 0; q < 8; ++q) {
        int idx = base + q;
        if (idx <= n) offset[idx] = run;
        run += v[q];
    }
}

// ===========================================================================
// build_ranks: standalone; ~22G atomics/s coherence-pipe floor (R7-R12).
// ===========================================================================
__global__ void build_ranks(const int* __restrict__ ei,
                            int* __restrict__ cnt,
                            unsigned short* __restrict__ rank_s,
                            unsigned short* __restrict__ rank_d)
{
    int e = blockIdx.x * 256 + threadIdx.x;   // NE == 3125*256 exactly
    int s = ei[e], d = ei[NE + e];
    rank_d[e] = (unsigned short)atomicAdd(cnt + d, 1);
    rank_s[e] = (unsigned short)atomicAdd(cnt + NN + s, 1);
}

// ===========================================================================
// build_perm: ONE 8B scattered store per edge (was 24B across two buffers).
// sperm64[spos] = {sl:4 | dstpos:20 | e:20}; sl = s&15 (blocks 16-aligned).
// RFO surface 19.2 MB -> 6.4 MB; ea_s/pack buffers deleted.
// ===========================================================================
__global__ void build_perm(const int* __restrict__ ei,
                           const int* __restrict__ off_all,
                           const unsigned short* __restrict__ rank_s,
                           const unsigned short* __restrict__ rank_d,
                           unsigned long long* __restrict__ sperm64)
{
    int e = blockIdx.x * 256 + threadIdx.x;
    int s = ei[e], d = ei[NE + e];
    int spos = off_all[NN + s] - NE + (int)rank_s[e];
    int dp   = off_all[d] + (int)rank_d[e];
    sperm64[spos] = ((unsigned long long)(s & 15) << 40)
                  | ((unsigned long long)(unsigned)dp << 20)
                  | (unsigned long long)(unsigned)e;
}

// ===========================================================================
// edge_fusedG<DIN>: block = out-edges of src nodes [16b,16b+16) (src-CSR).
// Phase 1: G for these 16 nodes INTO LDS from LDS-staged w2 (R14 lesson:
// direct-global phase 1 = 51M scattered vmem loads, 2x slower).
// Phase 2: chunked edge loop; sperm64 sequential read gives {sl,dp,e};
// ea gathered directly (L2/L3-resident read-only input);
// LDS remap -> full-64B-row stores to msgbuf (no RFO).
// ===========================================================================
template<int DIN>
__global__ __launch_bounds__(256) void edge_fusedG(
        const float* __restrict__ xin,    // [NN][DIN]
        const unsigned long long* __restrict__ sperm64, // [NE] src-sorted
        const float* __restrict__ ea,     // [NE][4] original order
        const float* __restrict__ eW1,    // [4][16]
        const float* __restrict__ eb1,    // [16]
        const float* __restrict__ eW2,    // [16][DIN*16]
        const float* __restrict__ eb2,    // [DIN*16]
        const int*   __restrict__ off_all,// src CSR at off_all[NN+s]
        float* __restrict__ msgbuf)       // [NE][16] dst-sorted rows
{
    constexpr int MROW = 260;
    constexpr int W2B  = DIN * 16 * 20 * 4;           // w2L bytes (phase 1)
    constexpr int SMB  = 16 * MROW * 4 + 256 * 4;     // smemM + sdp (phase 2)
    constexpr int UNIB = (W2B > SMB) ? W2B : SMB;
    __shared__ __align__(16) char uni[UNIB];
    float* w2L   = (float*)uni;                        // [(i*16+k)*20 + o]
    float* smemM = (float*)uni;                        // [16][MROW]
    int*   sdp   = (int*)(uni + 16 * MROW * 4);        // [256]
    __shared__ __align__(16) float4 G4[16 * 69];       // [sl*69 + ob*17 + k]
    __shared__ __align__(16) float4 xbL[16 * 5];       // [sl*5 + ob] (pad 5)
    __shared__ __align__(16) float  xL[16 * DIN];
    __shared__ __align__(16) float  b2L[DIN * 16];
    __shared__ __align__(16) float4 w1t[16];
    __shared__ __align__(16) float  b1s[16];

    int tid = threadIdx.x;
    int nb  = blockIdx.x * 16;                // first src node of block
    if (tid < 16) {
        w1t[tid] = make_float4(eW1[tid], eW1[16 + tid], eW1[32 + tid], eW1[48 + tid]);
        b1s[tid] = eb1[tid];
    }
    for (int t = tid; t < 16 * DIN * 16; t += 256) {
        int k = t / (DIN * 16);
        int rem = t - k * DIN * 16;
        int i = rem >> 4, o = rem & 15;
        w2L[(i * 16 + k) * 20 + o] = eW2[t];
    }
    for (int t = tid; t < DIN * 16; t += 256) b2L[t] = eb2[t];
    for (int t = tid; t < 16 * DIN; t += 256) xL[t] = xin[(size_t)nb * DIN + t];
    __syncthreads();

    // ---- phase 1: G + xb for 16 local nodes; thread (nl, k) ----
    {
        int nl = tid >> 4, k = tid & 15;
        const float* xrow = xL + nl * DIN;
#pragma unroll
        for (int ob = 0; ob < 4; ++ob) {
            float4 a4 = make_float4(0.f, 0.f, 0.f, 0.f);
#pragma unroll
            for (int i = 0; i < DIN; ++i) {
                const float4 w = *((const float4*)(w2L + (i * 16 + k) * 20) + ob);
                a4.x += xrow[i] * w.x; a4.y += xrow[i] * w.y;
                a4.z += xrow[i] * w.z; a4.w += xrow[i] * w.w;
            }
            G4[nl * 69 + ob * 17 + k] = a4;
        }
        if (k < 4) {
            int ob = k;
            const float4* b2v = (const float4*)b2L;
            float4 a4 = make_float4(0.f, 0.f, 0.f, 0.f);
#pragma unroll
            for (int i = 0; i < DIN; ++i) {
                float4 b = b2v[i * 4 + ob];
                a4.x += xrow[i] * b.x; a4.y += xrow[i] * b.y;
                a4.z += xrow[i] * b.z; a4.w += xrow[i] * b.w;
            }
            xbL[nl * 5 + ob] = a4;
        }
    }
    __syncthreads();   // w2L dead; uni becomes smemM/sdp

    // ---- phase 2: chunked edge loop over this block's src-CSR range ----
    int eBeg = off_all[NN + nb] - NE;
    int eEnd = off_all[NN + nb + 16] - NE;
    for (int cb = eBeg; cb < eEnd; cb += 256) {
        int pos = cb + tid;
        bool valid = pos < eEnd;
        unsigned long long pk = valid ? sperm64[pos] : 0ull;
        int e  = (int)(pk & 0xFFFFFu);
        int dp = (int)((pk >> 20) & 0xFFFFFu);
        int sl = (int)(pk >> 40);
        float4 a = valid ? ((const float4*)ea)[e] : make_float4(0.f, 0.f, 0.f, 0.f);

        float h[16];
#pragma unroll
        for (int j = 0; j < 16; ++j) {
            float4 w = w1t[j];
            float p = b1s[j] + a.x * w.x + a.y * w.y + a.z * w.z + a.w * w.w;
            h[j] = p * sigm(p);
        }
        float4 acc[4];
#pragma unroll
        for (int ob = 0; ob < 4; ++ob) acc[ob] = xbL[sl * 5 + ob];
#pragma unroll
        for (int k = 0; k < 16; ++k) {
            float hk = h[k];
#pragma unroll
            for (int ob = 0; ob < 4; ++ob) {
                float4 g = G4[sl * 69 + ob * 17 + k];
                acc[ob].x += hk * g.x; acc[ob].y += hk * g.y;
                acc[ob].z += hk * g.z; acc[ob].w += hk * g.w;
            }
        }
        sdp[tid] = valid ? dp : -1;
#pragma unroll
        for (int ob = 0; ob < 4; ++ob) {
            smemM[(ob * 4 + 0) * MROW + tid] = acc[ob].x;
            smemM[(ob * 4 + 1) * MROW + tid] = acc[ob].y;
            smemM[(ob * 4 + 2) * MROW + tid] = acc[ob].z;
            smemM[(ob * 4 + 3) * MROW + tid] = acc[ob].w;
        }
        __syncthreads();
#pragma unroll
        for (int r = 0; r < 16; ++r) {
            int le = r * 16 + (tid >> 4);
            int ch = tid & 15;
            int d2 = sdp[le];                      // 16-lane broadcast
            float v = smemM[ch * MROW + le];       // 2 lanes/bank: free
            if (d2 >= 0) msgbuf[(size_t)d2 * 16 + ch] = v;  // full 64B rows
        }
        __syncthreads();
    }
}

// ===========================================================================
// gather_L0: tiny-LDS, high-occupancy (R13 lesson: keep latency-bound
// gather OUT of the big-LDS edge kernel).
// ===========================================================================
__global__ __launch_bounds__(256) void gather_L0(
        const float* __restrict__ xin,    // [NN][8]
        const float* __restrict__ root,   // [8][16]
        const float* __restrict__ bias,   // [16]
        const int*   __restrict__ off_all,
        const float* __restrict__ msgbuf,
        float* __restrict__ x1)           // [NN][16]
{
    __shared__ __align__(16) float rootL[8 * 16];
    __shared__ __align__(16) float biasL[16];
    int tid = threadIdx.x;
    if (tid < 128) rootL[tid] = root[tid];
    if (tid < 16) biasL[tid] = bias[tid];
    __syncthreads();

    int ch = tid & 15;
    int n  = blockIdx.x * 16 + (tid >> 4);
    int s0 = off_all[n], e0 = off_all[n + 1];

    float acc = 0.f;
    for (int j = s0; j < e0; ++j)
        acc += msgbuf[(size_t)j * 16 + ch];
    float v = acc / fmaxf((float)(e0 - s0), 1.0f) + biasL[ch];
#pragma unroll
    for (int i = 0; i < 8; ++i)
        v += xin[(size_t)n * 8 + i] * rootL[i * 16 + ch];
    x1[(size_t)n * 16 + ch] = fmaxf(v, 0.f);
}

// ===========================================================================
// gather_final: contiguous dst-row sums + node update + output MLP.
// ===========================================================================
__global__ __launch_bounds__(256) void gather_final(
        const float* __restrict__ x1,     // [NN][16]
        const float* __restrict__ root,   // [16][16]
        const float* __restrict__ bias,   // [16]
        const int*   __restrict__ off_all,
        const float* __restrict__ msgbuf,
        const float* __restrict__ mW1,    // [16][16]
        const float* __restrict__ mb1,    // [16]
        const float* __restrict__ mW2,    // [16]
        const float* __restrict__ mb2,    // [1]
        float* __restrict__ out)          // [NN]
{
    __shared__ __align__(16) float rootL[256];
    __shared__ __align__(16) float biasL[16];
    __shared__ __align__(16) float w1m[256];
    __shared__ __align__(16) float b1m[16];
    __shared__ __align__(16) float w2m[16];
    __shared__ float b2m;
    int tid = threadIdx.x;
    rootL[tid] = root[tid];
    w1m[tid] = mW1[tid];
    if (tid < 16) { biasL[tid] = bias[tid]; b1m[tid] = mb1[tid]; w2m[tid] = mW2[tid]; }
    if (tid == 0) b2m = mb2[0];
    __syncthreads();

    int ch = tid & 15;
    int n  = blockIdx.x * 16 + (tid >> 4);
    int s0 = off_all[n], e0 = off_all[n + 1];

    float acc = 0.f;
    for (int j = s0; j < e0; ++j)
        acc += msgbuf[(size_t)j * 16 + ch];
    float v = acc / fmaxf((float)(e0 - s0), 1.0f) + biasL[ch];
#pragma unroll
    for (int i = 0; i < 16; ++i)
        v += x1[(size_t)n * 16 + i] * rootL[i * 16 + ch];
    v = fmaxf(v, 0.f);

    float z = b1m[ch];
#pragma unroll
    for (int o = 0; o < 16; ++o) {
        float vo = __shfl(v, o, 16);
        z += vo * w1m[o * 16 + ch];
    }
    float ss = z * sigm(z) * w2m[ch];
#pragma unroll
    for (int off = 8; off; off >>= 1) ss += __shfl_xor(ss, off, 16);
    if (ch == 0) out[n] = sigm(ss + b2m);
}

// ===========================================================================
// Host launch
// ===========================================================================
extern "C" void kernel_launch(void* const* d_in, const int* in_sizes, int n_in,
                              void* d_out, int out_size, void* d_ws, size_t ws_size,
                              hipStream_t stream) {
    const float* x     = (const float*)d_in[0];
    const int*   ei    = (const int*)  d_in[1];
    const float* ea    = (const float*)d_in[2];
    const float* eW1_0 = (const float*)d_in[3];
    const float* eb1_0 = (const float*)d_in[4];
    const float* eW2_0 = (const float*)d_in[5];
    const float* eb2_0 = (const float*)d_in[6];
    const float* root0 = (const float*)d_in[7];
    const float* bias0 = (const float*)d_in[8];
    const float* eW1_1 = (const float*)d_in[9];
    const float* eb1_1 = (const float*)d_in[10];
    const float* eW2_1 = (const float*)d_in[11];
    const float* eb2_1 = (const float*)d_in[12];
    const float* root1 = (const float*)d_in[13];
    const float* bias1 = (const float*)d_in[14];
    const float* mW1   = (const float*)d_in[15];
    const float* mb1   = (const float*)d_in[16];
    const float* mW2   = (const float*)d_in[17];
    const float* mb2   = (const float*)d_in[18];
    float* out = (float*)d_out;

    const int EG = NE / 256;   // 3125
    const int GG = NN / 16;    // 3125
    const int SN = 2 * NN;              // 100000 bins
    const int SB = (SN + 2047) / 2048;  // 49

    // ---- ws layout (4B words), total ~16.1M words = 64.4 MB ----
    int* W = (int*)d_ws;
    int*   off_all = W;                       // 100001 -> pad 100004
    int*   bsum    = W + 100004;              // 512
    unsigned short* rank_s = (unsigned short*)(W + 100516);  // NE u16
    unsigned short* rank_d = (unsigned short*)(W + 500516);  // NE u16
    unsigned long long* sperm64 = (unsigned long long*)(W + 900516); // NE u64
    float* x1      = (float*)(W + 2500516);   // [NN][16]
    float* msgbuf  = (float*)(W + 3300516);   // [NE][16]
    int*   cnt     = W + 3300516;             // SN ints, overlaid on msgbuf

    hipMemsetAsync(cnt, 0, SN * sizeof(int), stream);
    build_ranks<<<EG, 256, 0, stream>>>(ei, cnt, rank_s, rank_d);
    scan_k1<<<SB, 256, 0, stream>>>(cnt, SN, bsum);
    scan_k2<<<1, 512, 0, stream>>>(bsum, SB);
    scan_k3<<<SB, 256, 0, stream>>>(cnt, SN, bsum, off_all);
    build_perm<<<EG, 256, 0, stream>>>(ei, off_all, rank_s, rank_d, sperm64);

    // ---- layer 0 ----
    edge_fusedG<8><<<GG, 256, 0, stream>>>(x, sperm64, ea, eW1_0, eb1_0,
                                           eW2_0, eb2_0, off_all, msgbuf);
    gather_L0<<<GG, 256, 0, stream>>>(x, root0, bias0, off_all, msgbuf, x1);

    // ---- layer 1 ----
    edge_fusedG<16><<<GG, 256, 0, stream>>>(x1, sperm64, ea, eW1_1, eb1_1,
                                            eW2_1, eb2_1, off_all, msgbuf);
    gather_final<<<GG, 256, 0, stream>>>(x1, root1, bias1, off_all, msgbuf,
                                         mW1, mb1, mW2, mb2, out);
}

// Round 17
// 313.021 us; speedup vs baseline: 1.4341x; 1.0323x over previous
//
#include <hip/hip_runtime.h>
#include <hip/hip_fp16.h>

#define NN 50000
#define NE 800000

__device__ __forceinline__ float sigm(float v) { return 1.0f / (1.0f + __expf(-v)); }

// ===========================================================================
// Hierarchical exclusive scan over n=100000 bins, 2048 elems/block.
// ===========================================================================
__global__ void scan_k1(const int* __restrict__ cnt, int n, int* __restrict__ bsum)
{
    __shared__ int s[256];
    int t = threadIdx.x;
    int base = blockIdx.x * 2048 + t * 8;
    int sum = 0;
#pragma unroll
    for (int q = 0; q < 8; ++q) { int idx = base + q; if (idx < n) sum += cnt[idx]; }
    s[t] = sum;
    __syncthreads();
#pragma unroll
    for (int d = 128; d; d >>= 1) { if (t < d) s[t] += s[t + d]; __syncthreads(); }
    if (t == 0) bsum[blockIdx.x] = s[0];
}

__global__ void scan_k2(int* __restrict__ bsum, int nblocks)
{
    __shared__ int s[512];
    int t = threadIdx.x;
    int v = (t < nblocks) ? bsum[t] : 0;
    s[t] = v;
    __syncthreads();
#pragma unroll
    for (int d = 1; d < 512; d <<= 1) {
        int a = (t >= d) ? s[t - d] : 0;
        __syncthreads();
        s[t] += a;
        __syncthreads();
    }
    if (t < nblocks) bsum[t] = s[t] - v;   // exclusive
}

__global__ void scan_k3(const int* __restrict__ cnt, int n,
                        const int* __restrict__ bsum, int* __restrict__ offset)
{
    __shared__ int s[256];
    int t = threadIdx.x;
    int base = blockIdx.x * 2048 + t * 8;
    int v[8]; int sum = 0;
#pragma unroll
    for (int q = 0; q < 8; ++q) {
        int idx = base + q;
        v[q] = (idx < n) ? cnt[idx] : 0;
        sum += v[q];
    }
    s[t] = sum;
    __syncthreads();
#pragma unroll
    for (int d = 1; d < 256; d <<= 1) {
        int a = (t >= d) ? s[t - d] : 0;
        __syncthreads();
        s[t] += a;
        __syncthreads();
    }
    int run = bsum[blockIdx.x] + ((t > 0) ? s[t - 1] : 0);
#pragma unroll
    for (int q = 0; q < 8; ++q) {
        int idx = base + q;
        if (idx <= n) offset[idx] = run;
        run += v[q];
    }
}

// ===========================================================================
// build_ranks: standalone; ~22G atomics/s coherence-pipe floor (R7-R12).
// ===========================================================================
__global__ void build_ranks(const int* __restrict__ ei,
                            int* __restrict__ cnt,
                            unsigned short* __restrict__ rank_s,
                            unsigned short* __restrict__ rank_d)
{
    int e = blockIdx.x * 256 + threadIdx.x;   // NE == 3125*256 exactly
    int s = ei[e], d = ei[NE + e];
    rank_d[e] = (unsigned short)atomicAdd(cnt + d, 1);
    rank_s[e] = (unsigned short)atomicAdd(cnt + NN + s, 1);
}

// ===========================================================================
// build_perm: ONE 8B scattered store per edge.
// sperm64[spos] = {sl:4 | dstpos:20 | e:20}; sl = s&15 (blocks 16-aligned).
// ===========================================================================
__global__ void build_perm(const int* __restrict__ ei,
                           const int* __restrict__ off_all,
                           const unsigned short* __restrict__ rank_s,
                           const unsigned short* __restrict__ rank_d,
                           unsigned long long* __restrict__ sperm64)
{
    int e = blockIdx.x * 256 + threadIdx.x;
    int s = ei[e], d = ei[NE + e];
    int spos = off_all[NN + s] - NE + (int)rank_s[e];
    int dp   = off_all[d] + (int)rank_d[e];
    sperm64[spos] = ((unsigned long long)(s & 15) << 40)
                  | ((unsigned long long)(unsigned)dp << 20)
                  | (unsigned long long)(unsigned)e;
}

// ===========================================================================
// edge_fusedG<DIN>: block = out-edges of src nodes [16b,16b+16) (src-CSR).
// Phase 1: G for these 16 nodes INTO LDS from LDS-staged w2.
// Phase 2: chunked edge loop; msg computed fp32, STORED AS FP16 (32B rows =
// TCC write granule, still full-sector stores). 8 lanes/row pack __half2.
// ===========================================================================
template<int DIN>
__global__ __launch_bounds__(256) void edge_fusedG(
        const float* __restrict__ xin,    // [NN][DIN]
        const unsigned long long* __restrict__ sperm64, // [NE] src-sorted
        const float* __restrict__ ea,     // [NE][4] original order
        const float* __restrict__ eW1,    // [4][16]
        const float* __restrict__ eb1,    // [16]
        const float* __restrict__ eW2,    // [16][DIN*16]
        const float* __restrict__ eb2,    // [DIN*16]
        const int*   __restrict__ off_all,// src CSR at off_all[NN+s]
        __half* __restrict__ msgbuf)      // [NE][16] fp16 dst-sorted rows
{
    constexpr int MROW = 260;
    constexpr int W2B  = DIN * 16 * 20 * 4;           // w2L bytes (phase 1)
    constexpr int SMB  = 16 * MROW * 4 + 256 * 4;     // smemM + sdp (phase 2)
    constexpr int UNIB = (W2B > SMB) ? W2B : SMB;
    __shared__ __align__(16) char uni[UNIB];
    float* w2L   = (float*)uni;                        // [(i*16+k)*20 + o]
    float* smemM = (float*)uni;                        // [16][MROW]
    int*   sdp   = (int*)(uni + 16 * MROW * 4);        // [256]
    __shared__ __align__(16) float4 G4[16 * 69];       // [sl*69 + ob*17 + k]
    __shared__ __align__(16) float4 xbL[16 * 5];       // [sl*5 + ob] (pad 5)
    __shared__ __align__(16) float  xL[16 * DIN];
    __shared__ __align__(16) float  b2L[DIN * 16];
    __shared__ __align__(16) float4 w1t[16];
    __shared__ __align__(16) float  b1s[16];

    int tid = threadIdx.x;
    int nb  = blockIdx.x * 16;                // first src node of block
    if (tid < 16) {
        w1t[tid] = make_float4(eW1[tid], eW1[16 + tid], eW1[32 + tid], eW1[48 + tid]);
        b1s[tid] = eb1[tid];
    }
    for (int t = tid; t < 16 * DIN * 16; t += 256) {
        int k = t / (DIN * 16);
        int rem = t - k * DIN * 16;
        int i = rem >> 4, o = rem & 15;
        w2L[(i * 16 + k) * 20 + o] = eW2[t];
    }
    for (int t = tid; t < DIN * 16; t += 256) b2L[t] = eb2[t];
    for (int t = tid; t < 16 * DIN; t += 256) xL[t] = xin[(size_t)nb * DIN + t];
    __syncthreads();

    // ---- phase 1: G + xb for 16 local nodes; thread (nl, k) ----
    {
        int nl = tid >> 4, k = tid & 15;
        const float* xrow = xL + nl * DIN;
#pragma unroll
        for (int ob = 0; ob < 4; ++ob) {
            float4 a4 = make_float4(0.f, 0.f, 0.f, 0.f);
#pragma unroll
            for (int i = 0; i < DIN; ++i) {
                const float4 w = *((const float4*)(w2L + (i * 16 + k) * 20) + ob);
                a4.x += xrow[i] * w.x; a4.y += xrow[i] * w.y;
                a4.z += xrow[i] * w.z; a4.w += xrow[i] * w.w;
            }
            G4[nl * 69 + ob * 17 + k] = a4;
        }
        if (k < 4) {
            int ob = k;
            const float4* b2v = (const float4*)b2L;
            float4 a4 = make_float4(0.f, 0.f, 0.f, 0.f);
#pragma unroll
            for (int i = 0; i < DIN; ++i) {
                float4 b = b2v[i * 4 + ob];
                a4.x += xrow[i] * b.x; a4.y += xrow[i] * b.y;
                a4.z += xrow[i] * b.z; a4.w += xrow[i] * b.w;
            }
            xbL[nl * 5 + ob] = a4;
        }
    }
    __syncthreads();   // w2L dead; uni becomes smemM/sdp

    // ---- phase 2: chunked edge loop over this block's src-CSR range ----
    int eBeg = off_all[NN + nb] - NE;
    int eEnd = off_all[NN + nb + 16] - NE;
    for (int cb = eBeg; cb < eEnd; cb += 256) {
        int pos = cb + tid;
        bool valid = pos < eEnd;
        unsigned long long pk = valid ? sperm64[pos] : 0ull;
        int e  = (int)(pk & 0xFFFFFu);
        int dp = (int)((pk >> 20) & 0xFFFFFu);
        int sl = (int)(pk >> 40);
        float4 a = valid ? ((const float4*)ea)[e] : make_float4(0.f, 0.f, 0.f, 0.f);

        float h[16];
#pragma unroll
        for (int j = 0; j < 16; ++j) {
            float4 w = w1t[j];
            float p = b1s[j] + a.x * w.x + a.y * w.y + a.z * w.z + a.w * w.w;
            h[j] = p * sigm(p);
        }
        float4 acc[4];
#pragma unroll
        for (int ob = 0; ob < 4; ++ob) acc[ob] = xbL[sl * 5 + ob];
#pragma unroll
        for (int k = 0; k < 16; ++k) {
            float hk = h[k];
#pragma unroll
            for (int ob = 0; ob < 4; ++ob) {
                float4 g = G4[sl * 69 + ob * 17 + k];
                acc[ob].x += hk * g.x; acc[ob].y += hk * g.y;
                acc[ob].z += hk * g.z; acc[ob].w += hk * g.w;
            }
        }
        sdp[tid] = valid ? dp : -1;
#pragma unroll
        for (int ob = 0; ob < 4; ++ob) {
            smemM[(ob * 4 + 0) * MROW + tid] = acc[ob].x;
            smemM[(ob * 4 + 1) * MROW + tid] = acc[ob].y;
            smemM[(ob * 4 + 2) * MROW + tid] = acc[ob].z;
            smemM[(ob * 4 + 3) * MROW + tid] = acc[ob].w;
        }
        __syncthreads();
        // 8 lanes per row: lane packs channels (2p, 2p+1) into one __half2.
        // smemM banks: (8p + le) mod 32 -> 32 banks x 2-way = free (m136).
#pragma unroll
        for (int r = 0; r < 8; ++r) {
            int le = r * 32 + (tid >> 3);          // 32 rows per round
            int p  = tid & 7;
            int d2 = sdp[le];                      // 8-lane broadcast
            float v0 = smemM[(2 * p)     * MROW + le];
            float v1 = smemM[(2 * p + 1) * MROW + le];
            if (d2 >= 0) {
                __half2 hv = __floats2half2_rn(v0, v1);
                *((__half2*)(msgbuf + (size_t)d2 * 16) + p) = hv;  // 32B full-sector rows
            }
        }
        __syncthreads();
    }
}

// ===========================================================================
// gather_L0: tiny-LDS, high-occupancy; fp16 msg rows, fp32 accumulation.
// ===========================================================================
__global__ __launch_bounds__(256) void gather_L0(
        const float* __restrict__ xin,    // [NN][8]
        const float* __restrict__ root,   // [8][16]
        const float* __restrict__ bias,   // [16]
        const int*   __restrict__ off_all,
        const __half* __restrict__ msgbuf,
        float* __restrict__ x1)           // [NN][16]
{
    __shared__ __align__(16) float rootL[8 * 16];
    __shared__ __align__(16) float biasL[16];
    int tid = threadIdx.x;
    if (tid < 128) rootL[tid] = root[tid];
    if (tid < 16) biasL[tid] = bias[tid];
    __syncthreads();

    int ch = tid & 15;
    int n  = blockIdx.x * 16 + (tid >> 4);
    int s0 = off_all[n], e0 = off_all[n + 1];

    float acc = 0.f;
    for (int j = s0; j < e0; ++j)
        acc += __half2float(msgbuf[(size_t)j * 16 + ch]);
    float v = acc / fmaxf((float)(e0 - s0), 1.0f) + biasL[ch];
#pragma unroll
    for (int i = 0; i < 8; ++i)
        v += xin[(size_t)n * 8 + i] * rootL[i * 16 + ch];
    x1[(size_t)n * 16 + ch] = fmaxf(v, 0.f);
}

// ===========================================================================
// gather_final: fp16 msg rows + node update + output MLP.
// ===========================================================================
__global__ __launch_bounds__(256) void gather_final(
        const float* __restrict__ x1,     // [NN][16]
        const float* __restrict__ root,   // [16][16]
        const float* __restrict__ bias,   // [16]
        const int*   __restrict__ off_all,
        const __half* __restrict__ msgbuf,
        const float* __restrict__ mW1,    // [16][16]
        const float* __restrict__ mb1,    // [16]
        const float* __restrict__ mW2,    // [16]
        const float* __restrict__ mb2,    // [1]
        float* __restrict__ out)          // [NN]
{
    __shared__ __align__(16) float rootL[256];
    __shared__ __align__(16) float biasL[16];
    __shared__ __align__(16) float w1m[256];
    __shared__ __align__(16) float b1m[16];
    __shared__ __align__(16) float w2m[16];
    __shared__ float b2m;
    int tid = threadIdx.x;
    rootL[tid] = root[tid];
    w1m[tid] = mW1[tid];
    if (tid < 16) { biasL[tid] = bias[tid]; b1m[tid] = mb1[tid]; w2m[tid] = mW2[tid]; }
    if (tid == 0) b2m = mb2[0];
    __syncthreads();

    int ch = tid & 15;
    int n  = blockIdx.x * 16 + (tid >> 4);
    int s0 = off_all[n], e0 = off_all[n + 1];

    float acc = 0.f;
    for (int j = s0; j < e0; ++j)
        acc += __half2float(msgbuf[(size_t)j * 16 + ch]);
    float v = acc / fmaxf((float)(e0 - s0), 1.0f) + biasL[ch];
#pragma unroll
    for (int i = 0; i < 16; ++i)
        v += x1[(size_t)n * 16 + i] * rootL[i * 16 + ch];
    v = fmaxf(v, 0.f);

    float z = b1m[ch];
#pragma unroll
    for (int o = 0; o < 16; ++o) {
        float vo = __shfl(v, o, 16);
        z += vo * w1m[o * 16 + ch];
    }
    float ss = z * sigm(z) * w2m[ch];
#pragma unroll
    for (int off = 8; off; off >>= 1) ss += __shfl_xor(ss, off, 16);
    if (ch == 0) out[n] = sigm(ss + b2m);
}

// ===========================================================================
// Host launch
// ===========================================================================
extern "C" void kernel_launch(void* const* d_in, const int* in_sizes, int n_in,
                              void* d_out, int out_size, void* d_ws, size_t ws_size,
                              hipStream_t stream) {
    const float* x     = (const float*)d_in[0];
    const int*   ei    = (const int*)  d_in[1];
    const float* ea    = (const float*)d_in[2];
    const float* eW1_0 = (const float*)d_in[3];
    const float* eb1_0 = (const float*)d_in[4];
    const float* eW2_0 = (const float*)d_in[5];
    const float* eb2_0 = (const float*)d_in[6];
    const float* root0 = (const float*)d_in[7];
    const float* bias0 = (const float*)d_in[8];
    const float* eW1_1 = (const float*)d_in[9];
    const float* eb1_1 = (const float*)d_in[10];
    const float* eW2_1 = (const float*)d_in[11];
    const float* eb2_1 = (const float*)d_in[12];
    const float* root1 = (const float*)d_in[13];
    const float* bias1 = (const float*)d_in[14];
    const float* mW1   = (const float*)d_in[15];
    const float* mb1   = (const float*)d_in[16];
    const float* mW2   = (const float*)d_in[17];
    const float* mb2   = (const float*)d_in[18];
    float* out = (float*)d_out;

    const int EG = NE / 256;   // 3125
    const int GG = NN / 16;    // 3125
    const int SN = 2 * NN;              // 100000 bins
    const int SB = (SN + 2047) / 2048;  // 49

    // ---- ws layout (4B words), total ~9.3M words = 37 MB ----
    int* W = (int*)d_ws;
    int*   off_all = W;                       // 100001 -> pad 100004
    int*   bsum    = W + 100004;              // 512
    unsigned short* rank_s = (unsigned short*)(W + 100516);  // NE u16
    unsigned short* rank_d = (unsigned short*)(W + 500516);  // NE u16
    unsigned long long* sperm64 = (unsigned long long*)(W + 900516); // NE u64
    float*  x1     = (float*)(W + 2500516);   // [NN][16]
    __half* msgbuf = (__half*)(W + 3300516);  // [NE][16] fp16 = 6.4M words
    int*    cnt    = W + 3300516;             // SN ints, overlaid on msgbuf

    hipMemsetAsync(cnt, 0, SN * sizeof(int), stream);
    build_ranks<<<EG, 256, 0, stream>>>(ei, cnt, rank_s, rank_d);
    scan_k1<<<SB, 256, 0, stream>>>(cnt, SN, bsum);
    scan_k2<<<1, 512, 0, stream>>>(bsum, SB);
    scan_k3<<<SB, 256, 0, stream>>>(cnt, SN, bsum, off_all);
    build_perm<<<EG, 256, 0, stream>>>(ei, off_all, rank_s, rank_d, sperm64);

    // ---- layer 0 ----
    edge_fusedG<8><<<GG, 256, 0, stream>>>(x, sperm64, ea, eW1_0, eb1_0,
                                           eW2_0, eb2_0, off_all, msgbuf);
    gather_L0<<<GG, 256, 0, stream>>>(x, root0, bias0, off_all, msgbuf, x1);

    // ---- layer 1 ----
    edge_fusedG<16><<<GG, 256, 0, stream>>>(x1, sperm64, ea, eW1_1, eb1_1,
                                            eW2_1, eb2_1, off_all, msgbuf);
    gather_final<<<GG, 256, 0, stream>>>(x1, root1, bias1, off_all, msgbuf,
                                         mW1, mb1, mW2, mb2, out);
}

// Round 18
// 299.419 us; speedup vs baseline: 1.4993x; 1.0454x over previous
//
#include <hip/hip_runtime.h>
#include <hip/hip_fp16.h>

#define NN 50000
#define NE 800000

__device__ __forceinline__ float sigm(float v) { return 1.0f / (1.0f + __expf(-v)); }

// ===========================================================================
// Hierarchical exclusive scan over n=100000 bins, 2048 elems/block.
// k2 fused into k3: each k3 block re-scans the 49 block sums in LDS.
// ===========================================================================
__global__ void scan_k1(const int* __restrict__ cnt, int n, int* __restrict__ bsum)
{
    __shared__ int s[256];
    int t = threadIdx.x;
    int base = blockIdx.x * 2048 + t * 8;
    int sum = 0;
#pragma unroll
    for (int q = 0; q < 8; ++q) { int idx = base + q; if (idx < n) sum += cnt[idx]; }
    s[t] = sum;
    __syncthreads();
#pragma unroll
    for (int d = 128; d; d >>= 1) { if (t < d) s[t] += s[t + d]; __syncthreads(); }
    if (t == 0) bsum[blockIdx.x] = s[0];
}

__global__ void scan_k3(const int* __restrict__ cnt, int n,
                        const int* __restrict__ bsum, int nb,
                        int* __restrict__ offset)
{
    __shared__ int s[256];
    __shared__ int sb[64];
    int t = threadIdx.x;
    if (t < 64) sb[t] = (t < nb) ? bsum[t] : 0;
    int base = blockIdx.x * 2048 + t * 8;
    int v[8]; int sum = 0;
#pragma unroll
    for (int q = 0; q < 8; ++q) {
        int idx = base + q;
        v[q] = (idx < n) ? cnt[idx] : 0;
        sum += v[q];
    }
    s[t] = sum;
    __syncthreads();
    if (t == 0) {             // exclusive scan of 49 block sums (trivial)
        int run = 0;
        for (int i = 0; i < nb; ++i) { int x = sb[i]; sb[i] = run; run += x; }
    }
#pragma unroll
    for (int d = 1; d < 256; d <<= 1) {
        int a = (t >= d) ? s[t - d] : 0;
        __syncthreads();
        s[t] += a;
        __syncthreads();
    }
    int run = sb[blockIdx.x] + ((t > 0) ? s[t - 1] : 0);
#pragma unroll
    for (int q = 0; q < 8; ++q) {
        int idx = base + q;
        if (idx <= n) offset[idx] = run;
        run += v[q];
    }
}

// ===========================================================================
// build_ranks: standalone; memory-bound at the atomic write-through path
// (WRITE_SIZE = 1.6M x 32B sectors at ~800 GB/s ~= measured 68us; R7-R17).
// ===========================================================================
__global__ void build_ranks(const int* __restrict__ ei,
                            int* __restrict__ cnt,
                            unsigned short* __restrict__ rank_s,
                            unsigned short* __restrict__ rank_d)
{
    int e = blockIdx.x * 256 + threadIdx.x;   // NE == 3125*256 exactly
    int s = ei[e], d = ei[NE + e];
    rank_d[e] = (unsigned short)atomicAdd(cnt + d, 1);
    rank_s[e] = (unsigned short)atomicAdd(cnt + NN + s, 1);
}

// ===========================================================================
// build_perm: ONE 8B scattered store per edge.
// sperm64[spos] = {sl:4 | dstpos:20 | e:20}; sl = s&15 (blocks 16-aligned).
// ===========================================================================
__global__ void build_perm(const int* __restrict__ ei,
                           const int* __restrict__ off_all,
                           const unsigned short* __restrict__ rank_s,
                           const unsigned short* __restrict__ rank_d,
                           unsigned long long* __restrict__ sperm64)
{
    int e = blockIdx.x * 256 + threadIdx.x;
    int s = ei[e], d = ei[NE + e];
    int spos = off_all[NN + s] - NE + (int)rank_s[e];
    int dp   = off_all[d] + (int)rank_d[e];
    sperm64[spos] = ((unsigned long long)(s & 15) << 40)
                  | ((unsigned long long)(unsigned)dp << 20)
                  | (unsigned long long)(unsigned)e;
}

// ===========================================================================
// edge_fusedG<DIN>: block = out-edges of src nodes [16b,16b+16) (src-CSR).
// Phase 1: G for these 16 nodes INTO LDS from LDS-staged w2.
// Phase 2: chunked edge loop; msg computed fp32, stored fp16 (32B rows =
// TCC write granule, full-sector stores). 8 lanes/row pack __half2.
// ===========================================================================
template<int DIN>
__global__ __launch_bounds__(256) void edge_fusedG(
        const float* __restrict__ xin,    // [NN][DIN]
        const unsigned long long* __restrict__ sperm64, // [NE] src-sorted
        const float* __restrict__ ea,     // [NE][4] original order
        const float* __restrict__ eW1,    // [4][16]
        const float* __restrict__ eb1,    // [16]
        const float* __restrict__ eW2,    // [16][DIN*16]
        const float* __restrict__ eb2,    // [DIN*16]
        const int*   __restrict__ off_all,// src CSR at off_all[NN+s]
        __half* __restrict__ msgbuf)      // [NE][16] fp16 dst-sorted rows
{
    constexpr int MROW = 260;
    constexpr int W2B  = DIN * 16 * 20 * 4;           // w2L bytes (phase 1)
    constexpr int SMB  = 16 * MROW * 4 + 256 * 4;     // smemM + sdp (phase 2)
    constexpr int UNIB = (W2B > SMB) ? W2B : SMB;
    __shared__ __align__(16) char uni[UNIB];
    float* w2L   = (float*)uni;                        // [(i*16+k)*20 + o]
    float* smemM = (float*)uni;                        // [16][MROW]
    int*   sdp   = (int*)(uni + 16 * MROW * 4);        // [256]
    __shared__ __align__(16) float4 G4[16 * 69];       // [sl*69 + ob*17 + k]
    __shared__ __align__(16) float4 xbL[16 * 5];       // [sl*5 + ob] (pad 5)
    __shared__ __align__(16) float  xL[16 * DIN];
    __shared__ __align__(16) float  b2L[DIN * 16];
    __shared__ __align__(16) float4 w1t[16];
    __shared__ __align__(16) float  b1s[16];

    int tid = threadIdx.x;
    int nb  = blockIdx.x * 16;                // first src node of block
    if (tid < 16) {
        w1t[tid] = make_float4(eW1[tid], eW1[16 + tid], eW1[32 + tid], eW1[48 + tid]);
        b1s[tid] = eb1[tid];
    }
    for (int t = tid; t < 16 * DIN * 16; t += 256) {
        int k = t / (DIN * 16);
        int rem = t - k * DIN * 16;
        int i = rem >> 4, o = rem & 15;
        w2L[(i * 16 + k) * 20 + o] = eW2[t];
    }
    for (int t = tid; t < DIN * 16; t += 256) b2L[t] = eb2[t];
    for (int t = tid; t < 16 * DIN; t += 256) xL[t] = xin[(size_t)nb * DIN + t];
    __syncthreads();

    // ---- phase 1: G + xb for 16 local nodes; thread (nl, k) ----
    {
        int nl = tid >> 4, k = tid & 15;
        const float* xrow = xL + nl * DIN;
#pragma unroll
        for (int ob = 0; ob < 4; ++ob) {
            float4 a4 = make_float4(0.f, 0.f, 0.f, 0.f);
#pragma unroll
            for (int i = 0; i < DIN; ++i) {
                const float4 w = *((const float4*)(w2L + (i * 16 + k) * 20) + ob);
                a4.x += xrow[i] * w.x; a4.y += xrow[i] * w.y;
                a4.z += xrow[i] * w.z; a4.w += xrow[i] * w.w;
            }
            G4[nl * 69 + ob * 17 + k] = a4;
        }
        if (k < 4) {
            int ob = k;
            const float4* b2v = (const float4*)b2L;
            float4 a4 = make_float4(0.f, 0.f, 0.f, 0.f);
#pragma unroll
            for (int i = 0; i < DIN; ++i) {
                float4 b = b2v[i * 4 + ob];
                a4.x += xrow[i] * b.x; a4.y += xrow[i] * b.y;
                a4.z += xrow[i] * b.z; a4.w += xrow[i] * b.w;
            }
            xbL[nl * 5 + ob] = a4;
        }
    }
    __syncthreads();   // w2L dead; uni becomes smemM/sdp

    // ---- phase 2: chunked edge loop over this block's src-CSR range ----
    int eBeg = off_all[NN + nb] - NE;
    int eEnd = off_all[NN + nb + 16] - NE;
    for (int cb = eBeg; cb < eEnd; cb += 256) {
        int pos = cb + tid;
        bool valid = pos < eEnd;
        unsigned long long pk = valid ? sperm64[pos] : 0ull;
        int e  = (int)(pk & 0xFFFFFu);
        int dp = (int)((pk >> 20) & 0xFFFFFu);
        int sl = (int)(pk >> 40);
        float4 a = valid ? ((const float4*)ea)[e] : make_float4(0.f, 0.f, 0.f, 0.f);

        float h[16];
#pragma unroll
        for (int j = 0; j < 16; ++j) {
            float4 w = w1t[j];
            float p = b1s[j] + a.x * w.x + a.y * w.y + a.z * w.z + a.w * w.w;
            h[j] = p * sigm(p);
        }
        float4 acc[4];
#pragma unroll
        for (int ob = 0; ob < 4; ++ob) acc[ob] = xbL[sl * 5 + ob];
#pragma unroll
        for (int k = 0; k < 16; ++k) {
            float hk = h[k];
#pragma unroll
            for (int ob = 0; ob < 4; ++ob) {
                float4 g = G4[sl * 69 + ob * 17 + k];
                acc[ob].x += hk * g.x; acc[ob].y += hk * g.y;
                acc[ob].z += hk * g.z; acc[ob].w += hk * g.w;
            }
        }
        sdp[tid] = valid ? dp : -1;
#pragma unroll
        for (int ob = 0; ob < 4; ++ob) {
            smemM[(ob * 4 + 0) * MROW + tid] = acc[ob].x;
            smemM[(ob * 4 + 1) * MROW + tid] = acc[ob].y;
            smemM[(ob * 4 + 2) * MROW + tid] = acc[ob].z;
            smemM[(ob * 4 + 3) * MROW + tid] = acc[ob].w;
        }
        __syncthreads();
        // 8 lanes per row: lane packs channels (2p, 2p+1) into one __half2.
#pragma unroll
        for (int r = 0; r < 8; ++r) {
            int le = r * 32 + (tid >> 3);          // 32 rows per round
            int p  = tid & 7;
            int d2 = sdp[le];                      // 8-lane broadcast
            float v0 = smemM[(2 * p)     * MROW + le];
            float v1 = smemM[(2 * p + 1) * MROW + le];
            if (d2 >= 0) {
                __half2 hv = __floats2half2_rn(v0, v1);
                *((__half2*)(msgbuf + (size_t)d2 * 16) + p) = hv;  // 32B rows
            }
        }
        __syncthreads();
    }
}

// ===========================================================================
// Gather helper: 16-lane group per node; lanes 0-7 read row j (__half2 each),
// lanes 8-15 read row j+1 -> 64B contiguous per group per iteration, half
// the iterations; shfl_xor(8) merges halves, 2 shuffles redistribute to
// per-channel layout. fp32 accumulation throughout.
// ===========================================================================
__device__ __forceinline__ float gather_msg16(const __half* __restrict__ msgbuf,
                                              int s0, int e0, int tid)
{
    int half = (tid >> 3) & 1;
    int p    = tid & 7;
    float ax = 0.f, ay = 0.f;
    for (int j = s0 + half; j < e0; j += 2) {
        __half2 hv = *((const __half2*)(msgbuf + (size_t)j * 16) + p);
        float2 f = __half22float2(hv);
        ax += f.x; ay += f.y;
    }
    ax += __shfl_xor(ax, 8, 16);
    ay += __shfl_xor(ay, 8, 16);
    int ch = tid & 15;
    float vx = __shfl(ax, ch >> 1, 16);
    float vy = __shfl(ay, ch >> 1, 16);
    return (ch & 1) ? vy : vx;
}

// ===========================================================================
// gather_L0: tiny-LDS, high-occupancy; fp16 msg rows, fp32 accumulation.
// ===========================================================================
__global__ __launch_bounds__(256) void gather_L0(
        const float* __restrict__ xin,    // [NN][8]
        const float* __restrict__ root,   // [8][16]
        const float* __restrict__ bias,   // [16]
        const int*   __restrict__ off_all,
        const __half* __restrict__ msgbuf,
        float* __restrict__ x1)           // [NN][16]
{
    __shared__ __align__(16) float rootL[8 * 16];
    __shared__ __align__(16) float biasL[16];
    int tid = threadIdx.x;
    if (tid < 128) rootL[tid] = root[tid];
    if (tid < 16) biasL[tid] = bias[tid];
    __syncthreads();

    int ch = tid & 15;
    int n  = blockIdx.x * 16 + (tid >> 4);
    int s0 = off_all[n], e0 = off_all[n + 1];

    float acc = gather_msg16(msgbuf, s0, e0, tid);
    float v = acc / fmaxf((float)(e0 - s0), 1.0f) + biasL[ch];
#pragma unroll
    for (int i = 0; i < 8; ++i)
        v += xin[(size_t)n * 8 + i] * rootL[i * 16 + ch];
    x1[(size_t)n * 16 + ch] = fmaxf(v, 0.f);
}

// ===========================================================================
// gather_final: fp16 msg rows + node update + output MLP.
// ===========================================================================
__global__ __launch_bounds__(256) void gather_final(
        const float* __restrict__ x1,     // [NN][16]
        const float* __restrict__ root,   // [16][16]
        const float* __restrict__ bias,   // [16]
        const int*   __restrict__ off_all,
        const __half* __restrict__ msgbuf,
        const float* __restrict__ mW1,    // [16][16]
        const float* __restrict__ mb1,    // [16]
        const float* __restrict__ mW2,    // [16]
        const float* __restrict__ mb2,    // [1]
        float* __restrict__ out)          // [NN]
{
    __shared__ __align__(16) float rootL[256];
    __shared__ __align__(16) float biasL[16];
    __shared__ __align__(16) float w1m[256];
    __shared__ __align__(16) float b1m[16];
    __shared__ __align__(16) float w2m[16];
    __shared__ float b2m;
    int tid = threadIdx.x;
    rootL[tid] = root[tid];
    w1m[tid] = mW1[tid];
    if (tid < 16) { biasL[tid] = bias[tid]; b1m[tid] = mb1[tid]; w2m[tid] = mW2[tid]; }
    if (tid == 0) b2m = mb2[0];
    __syncthreads();

    int ch = tid & 15;
    int n  = blockIdx.x * 16 + (tid >> 4);
    int s0 = off_all[n], e0 = off_all[n + 1];

    float acc = gather_msg16(msgbuf, s0, e0, tid);
    float v = acc / fmaxf((float)(e0 - s0), 1.0f) + biasL[ch];
#pragma unroll
    for (int i = 0; i < 16; ++i)
        v += x1[(size_t)n * 16 + i] * rootL[i * 16 + ch];
    v = fmaxf(v, 0.f);

    float z = b1m[ch];
#pragma unroll
    for (int o = 0; o < 16; ++o) {
        float vo = __shfl(v, o, 16);
        z += vo * w1m[o * 16 + ch];
    }
    float ss = z * sigm(z) * w2m[ch];
#pragma unroll
    for (int off = 8; off; off >>= 1) ss += __shfl_xor(ss, off, 16);
    if (ch == 0) out[n] = sigm(ss + b2m);
}

// ===========================================================================
// Host launch
// ===========================================================================
extern "C" void kernel_launch(void* const* d_in, const int* in_sizes, int n_in,
                              void* d_out, int out_size, void* d_ws, size_t ws_size,
                              hipStream_t stream) {
    const float* x     = (const float*)d_in[0];
    const int*   ei    = (const int*)  d_in[1];
    const float* ea    = (const float*)d_in[2];
    const float* eW1_0 = (const float*)d_in[3];
    const float* eb1_0 = (const float*)d_in[4];
    const float* eW2_0 = (const float*)d_in[5];
    const float* eb2_0 = (const float*)d_in[6];
    const float* root0 = (const float*)d_in[7];
    const float* bias0 = (const float*)d_in[8];
    const float* eW1_1 = (const float*)d_in[9];
    const float* eb1_1 = (const float*)d_in[10];
    const float* eW2_1 = (const float*)d_in[11];
    const float* eb2_1 = (const float*)d_in[12];
    const float* root1 = (const float*)d_in[13];
    const float* bias1 = (const float*)d_in[14];
    const float* mW1   = (const float*)d_in[15];
    const float* mb1   = (const float*)d_in[16];
    const float* mW2   = (const float*)d_in[17];
    const float* mb2   = (const float*)d_in[18];
    float* out = (float*)d_out;

    const int EG = NE / 256;   // 3125
    const int GG = NN / 16;    // 3125
    const int SN = 2 * NN;              // 100000 bins
    const int SB = (SN + 2047) / 2048;  // 49

    // ---- ws layout (4B words), total ~9.3M words = 37 MB ----
    int* W = (int*)d_ws;
    int*   off_all = W;                       // 100001 -> pad 100004
    int*   bsum    = W + 100004;              // 512
    unsigned short* rank_s = (unsigned short*)(W + 100516);  // NE u16
    unsigned short* rank_d = (unsigned short*)(W + 500516);  // NE u16
    unsigned long long* sperm64 = (unsigned long long*)(W + 900516); // NE u64
    float*  x1     = (float*)(W + 2500516);   // [NN][16]
    __half* msgbuf = (__half*)(W + 3300516);  // [NE][16] fp16 = 6.4M words
    int*    cnt    = W + 3300516;             // SN ints, overlaid on msgbuf

    hipMemsetAsync(cnt, 0, SN * sizeof(int), stream);
    build_ranks<<<EG, 256, 0, stream>>>(ei, cnt, rank_s, rank_d);
    scan_k1<<<SB, 256, 0, stream>>>(cnt, SN, bsum);
    scan_k3<<<SB, 256, 0, stream>>>(cnt, SN, bsum, SB, off_all);
    build_perm<<<EG, 256, 0, stream>>>(ei, off_all, rank_s, rank_d, sperm64);

    // ---- layer 0 ----
    edge_fusedG<8><<<GG, 256, 0, stream>>>(x, sperm64, ea, eW1_0, eb1_0,
                                           eW2_0, eb2_0, off_all, msgbuf);
    gather_L0<<<GG, 256, 0, stream>>>(x, root0, bias0, off_all, msgbuf, x1);

    // ---- layer 1 ----
    edge_fusedG<16><<<GG, 256, 0, stream>>>(x1, sperm64, ea, eW1_1, eb1_1,
                                            eW2_1, eb2_1, off_all, msgbuf);
    gather_final<<<GG, 256, 0, stream>>>(x1, root1, bias1, off_all, msgbuf,
                                         mW1, mb1, mW2, mb2, out);
}